// Round 4
// baseline (291.275 us; speedup 1.0000x reference)
//
#include <hip/hip_runtime.h>
#include <hip/hip_bf16.h>

// B=2 H=16 S=2048 D=64, causal. Output = context (B,H,S,D) ++ attention (B,H,S,S), fp32.
// Uniform-work pair blocks; dbuf K/V in LDS; ONE raw barrier (lgkm-only) per kt-iter.

constexpr int SEQ = 2048;
constexpr int HD  = 64;
constexpr int NHEADS = 32;   // B*H
constexpr int QT  = 64;      // q-tile rows (also k-tile width)
constexpr int NT  = SEQ / QT;

typedef __bf16 bf16x8 __attribute__((ext_vector_type(8)));
typedef unsigned short u16x8 __attribute__((ext_vector_type(8)));
typedef unsigned short u16x4 __attribute__((ext_vector_type(4)));
typedef float f32x4 __attribute__((ext_vector_type(4)));
typedef unsigned short us;

__device__ __forceinline__ us f2bf(float x) {
  unsigned u = __builtin_bit_cast(unsigned, x);
  return (us)((u + 0x7fffu + ((u >> 16) & 1u)) >> 16);  // RNE
}
__device__ __forceinline__ float bf2f(us b) {
  return __builtin_bit_cast(float, (unsigned)b << 16);
}
// Barrier with LDS visibility only — deliberately NO vmcnt drain (in-flight
// nontemporal HBM stores / prefetch loads survive across it).
__device__ __forceinline__ void wg_barrier() {
  asm volatile("s_waitcnt lgkmcnt(0)" ::: "memory");
  __builtin_amdgcn_s_barrier();
  __builtin_amdgcn_sched_barrier(0);
}

__launch_bounds__(256, 2)
__global__ void attn_kernel(const float* __restrict__ Qg,
                            const float* __restrict__ Kg,
                            const float* __restrict__ Vg,
                            float* __restrict__ out) {
  const int pi = blockIdx.x;    // 0..15 : pair index (handles q-tiles pi and 31-pi)
  const int bh = blockIdx.y;
  const int t  = threadIdx.x;
  const int l  = t & 63;
  const int w  = t >> 6;        // wave 0..3, owns q-rows w*16..w*16+15
  const int l16 = l & 15;
  const int lg  = l >> 4;       // 0..3

  __shared__ __align__(16) us Qs[QT * HD];
  __shared__ __align__(16) us Ks[2][QT * HD];   // dbuf, b128-read swizzle
  __shared__ __align__(16) us Vs[2][QT * HD];   // dbuf, [key][d] u16-gather swizzle
  __shared__ __align__(16) us Ps[4][16 * QT];   // per-wave only (no cross-wave access)

  const size_t hoff = (size_t)bh * SEQ * HD;
  const float* Qh = Qg + hoff;
  const float* Kh = Kg + hoff;
  const float* Vh = Vg + hoff;
  float* ctx = out + hoff;
  float* att = out + (size_t)NHEADS * SEQ * HD + (size_t)bh * SEQ * SEQ;

  auto load_tile = [&](const float* src, f32x4 (&reg)[4]) {
    #pragma unroll
    for (int j = 0; j < 4; ++j) {
      const int f = t + 256 * j;
      reg[j] = *(const f32x4*)(src + (size_t)(f >> 4) * HD + 4 * (f & 15));
    }
  };
  auto write_k = [&](const f32x4 (&reg)[4], us* dst) {
    #pragma unroll
    for (int j = 0; j < 4; ++j) {
      const int f = t + 256 * j;
      const int r = f >> 4, c4 = f & 15;
      const int idx = (r * 64 + 4 * c4) ^ ((r & 7) << 3);
      u16x4 b = { f2bf(reg[j].x), f2bf(reg[j].y), f2bf(reg[j].z), f2bf(reg[j].w) };
      *(u16x4*)(&dst[idx]) = b;
    }
  };
  auto write_vv = [&](const f32x4 (&reg)[4], us* dst) {
    #pragma unroll
    for (int j = 0; j < 4; ++j) {
      const int f = t + 256 * j;
      const int r = f >> 4, c4 = f & 15;
      const int idx = (r * 64 + 4 * c4) ^ (((r >> 3) & 3) << 4);
      u16x4 b = { f2bf(reg[j].x), f2bf(reg[j].y), f2bf(reg[j].z), f2bf(reg[j].w) };
      *(u16x4*)(&dst[idx]) = b;
    }
  };

  const float sc = 0.125f;  // 1/sqrt(64)

  for (int half = 0; half < 2; ++half) {
    const int qt = half ? (NT - 1 - pi) : pi;
    const int qbase = qt * QT;
    const int qg = qbase + w * 16 + l16;   // this lane's q-row (S^T layout)

    __syncthreads();   // between halves: full drain is fine (2 per kernel)

    // ---- zero-fill masked columns (nontemporal, full-line coalesced) ----
    {
      const int zc0 = (qt + 1) * QT;
      const int nz4 = (SEQ - zc0) >> 2;
      for (int r = 0; r < QT; ++r) {
        float* rowp = att + (size_t)(qbase + r) * SEQ + zc0;
        for (int c = t; c < nz4; c += 256)
          __builtin_nontemporal_store((f32x4){0.f, 0.f, 0.f, 0.f}, (f32x4*)(rowp + 4 * c));
      }
    }

    // ---- stage Q; preload Q B-fragments ----
    {
      f32x4 qreg[4];
      load_tile(Qh + (size_t)qbase * HD, qreg);
      write_k(qreg, Qs);
    }
    wg_barrier();

    bf16x8 aq[2];
    #pragma unroll
    for (int ks = 0; ks < 2; ++ks) {
      const int qr = w * 16 + l16;
      const int d0 = ks * 32 + lg * 8;
      const int idx = (qr * 64 + d0) ^ ((qr & 7) << 3);
      aq[ks] = __builtin_bit_cast(bf16x8, *(const u16x8*)(&Qs[idx]));
    }

    // ================= phase 1: row sums of exp(scores) =================
    float rsum = 0.f;
    {
      f32x4 ka[4], kb[4];
      load_tile(Kh, ka);
      write_k(ka, Ks[0]);
      if (qt >= 1) load_tile(Kh + (size_t)QT * HD, ka);   // tile 1 -> ka
      wg_barrier();

      auto body = [&](int kt, const us* rbuf, us* wbuf, f32x4 (&regW)[4], f32x4 (&regL)[4]) {
        if (kt + 2 <= qt) load_tile(Kh + (size_t)(kt + 2) * QT * HD, regL);
        const int kb_ = kt * QT;
        #pragma unroll
        for (int ct = 0; ct < 4; ++ct) {
          f32x4 acc = {0.f, 0.f, 0.f, 0.f};
          #pragma unroll
          for (int ks = 0; ks < 2; ++ks) {
            const int kr = ct * 16 + l16;
            const int d0 = ks * 32 + lg * 8;
            const int idx = (kr * 64 + d0) ^ ((kr & 7) << 3);
            bf16x8 bk = __builtin_bit_cast(bf16x8, *(const u16x8*)(&rbuf[idx]));
            acc = __builtin_amdgcn_mfma_f32_16x16x32_bf16(bk, aq[ks], acc, 0, 0, 0);  // S^T
          }
          const int kg0 = kb_ + ct * 16 + lg * 4;
          #pragma unroll
          for (int r = 0; r < 4; ++r) {
            float e = __expf(acc[r] * sc);
            rsum += (kg0 + r <= qg) ? e : 0.f;
          }
        }
        if (kt < qt) write_k(regW, wbuf);   // writes before barrier; read next iter
        wg_barrier();
      };
      for (int kt = 0; kt <= qt; ++kt) {
        if ((kt & 1) == 0) body(kt, Ks[0], Ks[1], ka, kb);
        else               body(kt, Ks[1], Ks[0], kb, ka);
      }
    }
    rsum += __shfl_xor(rsum, 16);
    rsum += __shfl_xor(rsum, 32);
    const float inv = 1.f / rsum;

    // ================= phase 2: P -> att + O = P·V =================
    f32x4 oacc[4];
    #pragma unroll
    for (int ct = 0; ct < 4; ++ct) oacc[ct] = (f32x4){0.f, 0.f, 0.f, 0.f};

    {
      f32x4 ka[4], kb[4], va[4], vb[4];
      load_tile(Kh, ka);
      load_tile(Vh, va);
      write_k(ka, Ks[0]);
      write_vv(va, Vs[0]);
      if (qt >= 1) { load_tile(Kh + (size_t)QT * HD, ka);
                     load_tile(Vh + (size_t)QT * HD, va); }
      wg_barrier();

      auto body = [&](int kt, const us* krb, us* kwb, const us* vrb, us* vwb,
                      f32x4 (&kW)[4], f32x4 (&vW)[4], f32x4 (&kL)[4], f32x4 (&vL)[4]) {
        if (kt + 2 <= qt) {
          load_tile(Kh + (size_t)(kt + 2) * QT * HD, kL);
          load_tile(Vh + (size_t)(kt + 2) * QT * HD, vL);
        }
        const int kb_ = kt * QT;

        // QK^T (swapped) -> normalized P -> Ps (own-wave strip)
        #pragma unroll
        for (int ct = 0; ct < 4; ++ct) {
          f32x4 acc = {0.f, 0.f, 0.f, 0.f};
          #pragma unroll
          for (int ks = 0; ks < 2; ++ks) {
            const int kr = ct * 16 + l16;
            const int d0 = ks * 32 + lg * 8;
            const int idx = (kr * 64 + d0) ^ ((kr & 7) << 3);
            bf16x8 bk = __builtin_bit_cast(bf16x8, *(const u16x8*)(&krb[idx]));
            acc = __builtin_amdgcn_mfma_f32_16x16x32_bf16(bk, aq[ks], acc, 0, 0, 0);
          }
          const int kg0 = kb_ + ct * 16 + lg * 4;
          u16x4 pb;
          #pragma unroll
          for (int r = 0; r < 4; ++r) {
            float e = __expf(acc[r] * sc) * inv;
            pb[r] = f2bf((kg0 + r <= qg) ? e : 0.f);
          }
          const int pidx = (l16 * 64 + ct * 16 + lg * 4) ^ ((l16 & 7) << 3);
          *(u16x4*)(&Ps[w][pidx]) = pb;
        }

        // att copy: OWN-wave rows only (no barrier needed), full-line nt stores
        #pragma unroll
        for (int j = 0; j < 4; ++j) {
          const int rloc = lg + 4 * j;    // rows 4j..4j+3, 16 lanes (l16) each -> 256B/row
          const int idx = (rloc * 64 + 4 * l16) ^ ((rloc & 7) << 3);
          u16x4 p4 = *(const u16x4*)(&Ps[w][idx]);
          f32x4 pv = { bf2f(p4[0]), bf2f(p4[1]), bf2f(p4[2]), bf2f(p4[3]) };
          __builtin_nontemporal_store(pv,
              (f32x4*)(att + (size_t)(qbase + w * 16 + rloc) * SEQ + kb_ + 4 * l16));
        }

        // PV (swapped): A = V^T (2-way-free u16 gather), B = P^T (own-wave)
        #pragma unroll
        for (int ct = 0; ct < 4; ++ct) {
          #pragma unroll
          for (int ks = 0; ks < 2; ++ks) {
            const int key0 = ks * 32 + lg * 8;
            const int pidx = (l16 * 64 + key0) ^ ((l16 & 7) << 3);
            bf16x8 pa = __builtin_bit_cast(bf16x8, *(const u16x8*)(&Ps[w][pidx]));
            bf16x8 av;
            const int dcol = ct * 16 + l16;
            const int xorv = ((key0 >> 3) & 3) << 4;
            #pragma unroll
            for (int jj = 0; jj < 8; ++jj)
              av[jj] = __builtin_bit_cast(__bf16, vrb[((key0 + jj) * 64 + dcol) ^ xorv]);
            oacc[ct] = __builtin_amdgcn_mfma_f32_16x16x32_bf16(av, pa, oacc[ct], 0, 0, 0);
          }
        }

        if (kt < qt) { write_k(kW, kwb); write_vv(vW, vwb); }  // before barrier
        wg_barrier();
      };
      for (int kt = 0; kt <= qt; ++kt) {
        if ((kt & 1) == 0) body(kt, Ks[0], Ks[1], Vs[0], Vs[1], ka, va, kb, vb);
        else               body(kt, Ks[1], Ks[0], Vs[1], Vs[0], kb, vb, ka, va);
      }
    }

    // ---- write context (nontemporal dwordx4) ----
    #pragma unroll
    for (int ct = 0; ct < 4; ++ct)
      __builtin_nontemporal_store(oacc[ct],
          (f32x4*)(ctx + (size_t)qg * HD + ct * 16 + lg * 4));
  }
}

extern "C" void kernel_launch(void* const* d_in, const int* in_sizes, int n_in,
                              void* d_out, int out_size, void* d_ws, size_t ws_size,
                              hipStream_t stream) {
  const float* Q = (const float*)d_in[0];
  const float* K = (const float*)d_in[1];
  const float* V = (const float*)d_in[2];
  float* out = (float*)d_out;
  dim3 grid(NT / 2, NHEADS);
  attn_kernel<<<grid, dim3(256), 0, stream>>>(Q, K, V, out);
}